// Round 1
// baseline (844.310 us; speedup 1.0000x reference)
//
#include <hip/hip_runtime.h>
#include <math.h>

#define BB   8
#define CIN  96
#define DIN  192
#define HH   64
#define WW   64
#define LL   4096
#define KK   4
#define RR   6
#define COUT 96

__device__ __forceinline__ float sigf(float x) { return 1.0f / (1.0f + __expf(-x)); }
__device__ __forceinline__ float softplusf_(float x) {
  // logaddexp(x, 0) = max(x,0) + log1p(exp(-|x|))
  return fmaxf(x, 0.0f) + log1pf(__expf(-fabsf(x)));
}

// ---------------------------------------------------------------------------
// Generic per-pixel GEMM: out[b,o,p] = sum_c in[b,c,p] * W[o,c]
// grid: (LL/1024, O/8, BB), block 256. Each thread: 4 pixels x 8 outputs.
// ---------------------------------------------------------------------------
template <int C>
__global__ __launch_bounds__(256) void gemm_pix_k(const float* __restrict__ in,
                                                  const float* __restrict__ W,
                                                  float* __restrict__ out, int O) {
  __shared__ float sW[C * 8];
  const int tid = threadIdx.x;
  const int b  = blockIdx.z;
  const int o0 = blockIdx.y * 8;
  const int p0 = blockIdx.x * 1024;
  for (int idx = tid; idx < C * 8; idx += 256) {
    int c = idx >> 3, j = idx & 7;
    sW[idx] = W[(o0 + j) * C + c];
  }
  __syncthreads();
  float acc[4][8];
#pragma unroll
  for (int jp = 0; jp < 4; ++jp)
#pragma unroll
    for (int j = 0; j < 8; ++j) acc[jp][j] = 0.0f;
  const float* inb = in + (size_t)b * C * LL + p0 + tid;
#pragma unroll 2
  for (int c = 0; c < C; ++c) {
    float xv[4];
#pragma unroll
    for (int jp = 0; jp < 4; ++jp) xv[jp] = inb[(size_t)c * LL + jp * 256];
    const float4 w0 = *(const float4*)&sW[c * 8];
    const float4 w1 = *(const float4*)&sW[c * 8 + 4];
#pragma unroll
    for (int jp = 0; jp < 4; ++jp) {
      acc[jp][0] = fmaf(xv[jp], w0.x, acc[jp][0]);
      acc[jp][1] = fmaf(xv[jp], w0.y, acc[jp][1]);
      acc[jp][2] = fmaf(xv[jp], w0.z, acc[jp][2]);
      acc[jp][3] = fmaf(xv[jp], w0.w, acc[jp][3]);
      acc[jp][4] = fmaf(xv[jp], w1.x, acc[jp][4]);
      acc[jp][5] = fmaf(xv[jp], w1.y, acc[jp][5]);
      acc[jp][6] = fmaf(xv[jp], w1.z, acc[jp][6]);
      acc[jp][7] = fmaf(xv[jp], w1.w, acc[jp][7]);
    }
  }
  float* ob = out + (size_t)b * O * LL + p0 + tid;
#pragma unroll
  for (int j = 0; j < 8; ++j)
#pragma unroll
    for (int jp = 0; jp < 4; ++jp) ob[(size_t)(o0 + j) * LL + jp * 256] = acc[jp][j];
}

// ---------------------------------------------------------------------------
// Depthwise 3x3 conv (SAME, zero pad) + bias + SiLU.
// in: xz[:, 0:DIN] layout [B,384,L]; out xc [B,DIN,L].
// ---------------------------------------------------------------------------
__global__ __launch_bounds__(256) void dwconv_silu_k(const float* __restrict__ xz,
                                                     const float* __restrict__ cw,
                                                     const float* __restrict__ cb,
                                                     float* __restrict__ xc) {
  int idx = blockIdx.x * 256 + threadIdx.x;  // B*DIN*LL
  int p  = idx & (LL - 1);
  int bd = idx >> 12;
  int d  = bd % DIN;
  int b  = bd / DIN;
  int h = p >> 6, w = p & 63;
  const float* xp = xz + ((size_t)b * 384 + d) * LL;
  float s = cb[d];
#pragma unroll
  for (int dh = -1; dh <= 1; ++dh) {
    int hh = h + dh;
    if (hh < 0 || hh >= HH) continue;
#pragma unroll
    for (int dw = -1; dw <= 1; ++dw) {
      int ww = w + dw;
      if (ww < 0 || ww >= WW) continue;
      s = fmaf(xp[hh * WW + ww], cw[d * 9 + (dh + 1) * 3 + (dw + 1)], s);
    }
  }
  xc[((size_t)b * DIN + d) * LL + p] = s * sigf(s);
}

// ---------------------------------------------------------------------------
// PriorToWeights MLP: prior[B,4,L] -> Wg[B,4,L] = 1 + s*(sigmoid(mlp)-1)
// ---------------------------------------------------------------------------
__global__ __launch_bounds__(256) void p2w_k(const float* __restrict__ prior,
                                             const float* __restrict__ alpha,
                                             const float* __restrict__ w1,
                                             const float* __restrict__ b1,
                                             const float* __restrict__ bnw,
                                             const float* __restrict__ bnb,
                                             const float* __restrict__ bnm,
                                             const float* __restrict__ bnv,
                                             const float* __restrict__ w2,
                                             const float* __restrict__ b2,
                                             float* __restrict__ Wg) {
  int idx = blockIdx.x * 256 + threadIdx.x;  // B*LL
  int p = idx & (LL - 1);
  int b = idx >> 12;
  float pr[4];
#pragma unroll
  for (int c = 0; c < 4; ++c) pr[c] = prior[((size_t)b * 4 + c) * LL + p];
  float s = sigf(alpha[0]);
  float g2[4];
#pragma unroll
  for (int j = 0; j < 4; ++j) g2[j] = b2[j];
  for (int o = 0; o < 32; ++o) {
    float g = b1[o];
#pragma unroll
    for (int c = 0; c < 4; ++c) g = fmaf(pr[c], w1[o * 4 + c], g);
    g = (g - bnm[o]) * rsqrtf(bnv[o] + 1e-5f) * bnw[o] + bnb[o];
    g = fmaxf(g, 0.0f);
#pragma unroll
    for (int j = 0; j < 4; ++j) g2[j] = fmaf(g, w2[j * 32 + o], g2[j]);
  }
#pragma unroll
  for (int j = 0; j < 4; ++j)
    Wg[((size_t)b * 4 + j) * LL + p] = 1.0f + s * (sigf(g2[j]) - 1.0f);
}

// ---------------------------------------------------------------------------
// x_proj: proj[b,k,c,p] = sum_d xc[b,d,p] * xpw[k,c,d]   (pixel-indexed!)
// block 256 = 64 pixels x 4 k; grid (LL/64, BB)
// ---------------------------------------------------------------------------
__global__ __launch_bounds__(256) void xproj_k(const float* __restrict__ xc,
                                               const float* __restrict__ xpw,
                                               float* __restrict__ proj) {
  __shared__ float sW[KK * DIN * 8];  // [k][d][c], 24 KB
  const int tid = threadIdx.x;
  for (int idx = tid; idx < KK * DIN * 8; idx += 256) {
    int k = idx / (DIN * 8);
    int rem = idx % (DIN * 8);
    int d = rem >> 3, c = rem & 7;
    sW[idx] = xpw[(k * 8 + c) * DIN + d];
  }
  __syncthreads();
  const int b = blockIdx.y;
  const int p = blockIdx.x * 64 + (tid & 63);
  const int k = tid >> 6;
  float acc[8];
#pragma unroll
  for (int c = 0; c < 8; ++c) acc[c] = 0.0f;
  const float* xb = xc + (size_t)b * DIN * LL + p;
  for (int d = 0; d < DIN; ++d) {
    float xv = xb[(size_t)d * LL];
    const float4 w0 = *(const float4*)&sW[(k * DIN + d) * 8];
    const float4 w1 = *(const float4*)&sW[(k * DIN + d) * 8 + 4];
    acc[0] = fmaf(xv, w0.x, acc[0]);
    acc[1] = fmaf(xv, w0.y, acc[1]);
    acc[2] = fmaf(xv, w0.z, acc[2]);
    acc[3] = fmaf(xv, w0.w, acc[3]);
    acc[4] = fmaf(xv, w1.x, acc[4]);
    acc[5] = fmaf(xv, w1.y, acc[5]);
    acc[6] = fmaf(xv, w1.z, acc[6]);
    acc[7] = fmaf(xv, w1.w, acc[7]);
  }
  float* pb = proj + ((size_t)(b * KK + k)) * 8 * LL + p;
#pragma unroll
  for (int c = 0; c < 8; ++c) pb[(size_t)c * LL] = acc[c];
}

__global__ __launch_bounds__(256) void zero_k(float* __restrict__ p, int n) {
  int i = blockIdx.x * 256 + threadIdx.x;
  if (i < n) p[i] = 0.0f;
}

// ---------------------------------------------------------------------------
// Chunked parallel selective scan (N=1), one block per (b,k,d).
// thread t owns l = t*16 .. t*16+15. Local scan -> block Hillis-Steele over
// linear-fn composition (P,H) -> fixup -> gated atomic merge into ym[b,d,pix].
// ---------------------------------------------------------------------------
__device__ __forceinline__ int dir_map(int k, int l) {
  if (k == 0) return l;
  if (k == 1) return ((l & 63) << 6) | (l >> 6);
  if (k == 2) return LL - 1 - l;
  int lr = LL - 1 - l;
  return ((lr & 63) << 6) | (lr >> 6);
}

__global__ __launch_bounds__(256) void scan_k(const float* __restrict__ xc,
                                              const float* __restrict__ proj,
                                              const float* __restrict__ Wg,
                                              const float* __restrict__ dtw,
                                              const float* __restrict__ dtb,
                                              const float* __restrict__ A_logs,
                                              const float* __restrict__ Ds,
                                              float* __restrict__ ym) {
  const int d = blockIdx.x;
  const int k = blockIdx.y;
  const int b = blockIdx.z;
  const int t = threadIdx.x;
  const int kd = k * DIN + d;
  float wr[6];
#pragma unroll
  for (int r = 0; r < 6; ++r) wr[r] = dtw[kd * 6 + r];
  const float bias = dtb[kd];
  const float Aa = -__expf(A_logs[kd]);
  const float Dv = Ds[kd];
  const float* xcb = xc + ((size_t)b * DIN + d) * LL;
  const float* prb = proj + ((size_t)(b * KK + k)) * 8 * LL;
  const float* wgb = Wg + ((size_t)b * KK + k) * LL;

  float P[16], Hl[16];
  float Pr = 1.0f, Hr = 0.0f;
  const int l0 = t * 16;
#pragma unroll
  for (int i = 0; i < 16; ++i) {
    int l = l0 + i;
    int p = dir_map(k, l);
    float xv = xcb[p];
    float dtr = bias;
#pragma unroll
    for (int r = 0; r < 6; ++r) dtr = fmaf(prb[(size_t)r * LL + p], wr[r], dtr);
    float Bv = prb[(size_t)6 * LL + p];
    float dt = softplusf_(dtr);
    float a = __expf(dt * Aa);
    float bx = dt * Bv * xv;
    Hr = fmaf(a, Hr, bx);
    Pr *= a;
    P[i] = Pr;
    Hl[i] = Hr;
  }
  __shared__ float sP[256], sH[256];
  float Pt = Pr, Ht = Hr;
  sP[t] = Pt;
  sH[t] = Ht;
#pragma unroll
  for (int off = 1; off < 256; off <<= 1) {
    __syncthreads();
    float pl = 1.0f, hl = 0.0f;
    if (t >= off) { pl = sP[t - off]; hl = sH[t - off]; }
    __syncthreads();
    if (t >= off) {
      Ht = fmaf(Pt, hl, Ht);  // compose: self after left (uses OLD Pt)
      Pt *= pl;
    }
    sP[t] = Pt;
    sH[t] = Ht;
  }
  __syncthreads();
  const float h0 = (t == 0) ? 0.0f : sH[t - 1];
  float* ymb = ym + ((size_t)b * DIN + d) * LL;
#pragma unroll
  for (int i = 0; i < 16; ++i) {
    int l = l0 + i;
    int p = dir_map(k, l);
    float xv = xcb[p];
    float Cv = prb[(size_t)7 * LL + p];
    float h = fmaf(P[i], h0, Hl[i]);
    float y = fmaf(h, Cv, Dv * xv) * wgb[l];  // (h*C + D*x) * Wdir(l row-major)
    atomicAdd(&ymb[p], y);
  }
}

// ---------------------------------------------------------------------------
// LayerNorm over channels + * silu(z). block: 64 pixels x 4 channel-groups.
// ---------------------------------------------------------------------------
__global__ __launch_bounds__(256) void ln_silu_k(const float* __restrict__ ym,
                                                 const float* __restrict__ xz,
                                                 const float* __restrict__ gamma,
                                                 const float* __restrict__ beta,
                                                 float* __restrict__ u) {
  const int b = blockIdx.y;
  const int p = blockIdx.x * 64 + (threadIdx.x & 63);
  const int g = threadIdx.x >> 6;
  const float* yb = ym + (size_t)b * DIN * LL + p;
  float sum = 0.0f, ss = 0.0f;
  for (int d = g * 48; d < g * 48 + 48; ++d) {
    float v = yb[(size_t)d * LL];
    sum += v;
    ss = fmaf(v, v, ss);
  }
  __shared__ float sS[4][64], sQ[4][64];
  sS[g][threadIdx.x & 63] = sum;
  sQ[g][threadIdx.x & 63] = ss;
  __syncthreads();
  int px = threadIdx.x & 63;
  sum = sS[0][px] + sS[1][px] + sS[2][px] + sS[3][px];
  ss  = sQ[0][px] + sQ[1][px] + sQ[2][px] + sQ[3][px];
  const float mu = sum * (1.0f / DIN);
  float var = ss * (1.0f / DIN) - mu * mu;
  const float rstd = rsqrtf(fmaxf(var, 0.0f) + 1e-5f);
  const float* zb = xz + ((size_t)b * 384 + DIN) * LL + p;
  float* ub = u + (size_t)b * DIN * LL + p;
  for (int d = g * 48; d < g * 48 + 48; ++d) {
    float v = yb[(size_t)d * LL];
    float z = zb[(size_t)d * LL];
    float tn = fmaf((v - mu) * rstd, gamma[d], beta[d]);
    ub[(size_t)d * LL] = tn * (z * sigf(z));
  }
}

// ---------------------------------------------------------------------------
extern "C" void kernel_launch(void* const* d_in, const int* in_sizes, int n_in,
                              void* d_out, int out_size, void* d_ws, size_t ws_size,
                              hipStream_t stream) {
  const float* x      = (const float*)d_in[0];
  const float* prior  = (const float*)d_in[1];
  const float* alpha  = (const float*)d_in[2];
  const float* ipw    = (const float*)d_in[3];
  const float* cw     = (const float*)d_in[4];
  const float* cb     = (const float*)d_in[5];
  const float* xpw    = (const float*)d_in[6];
  const float* dtw    = (const float*)d_in[7];
  const float* dtb    = (const float*)d_in[8];
  const float* A_logs = (const float*)d_in[9];
  const float* Ds     = (const float*)d_in[10];
  const float* onw    = (const float*)d_in[11];
  const float* onb    = (const float*)d_in[12];
  const float* opw    = (const float*)d_in[13];
  const float* w1     = (const float*)d_in[14];
  const float* b1     = (const float*)d_in[15];
  const float* bnw    = (const float*)d_in[16];
  const float* bnb    = (const float*)d_in[17];
  const float* bnm    = (const float*)d_in[18];
  const float* bnv    = (const float*)d_in[19];
  const float* w2     = (const float*)d_in[20];
  const float* b2     = (const float*)d_in[21];
  float* out = (float*)d_out;

  char* ws = (char*)d_ws;
  float* xz   = (float*)(ws);                                 // [B,384,L]  50.3 MB
  float* xc   = (float*)(ws + 50331648);                      // [B,192,L]  25.2 MB
  float* proj = (float*)(ws + 50331648 + 25165824);           // [B,4,8,L]   4.2 MB
  float* Wgb  = (float*)(ws + 50331648 + 25165824 + 4194304); // [B,4,L]     0.5 MB
  float* ym   = (float*)(ws + 50331648 + 25165824 + 4194304 + 524288);  // [B,192,L]
  float* u    = xc;  // reuse: xc dead after scan_k

  // 1) in_proj GEMM: [B,96,L] -> [B,384,L]
  gemm_pix_k<CIN><<<dim3(LL / 1024, 384 / 8, BB), 256, 0, stream>>>(x, ipw, xz, 384);
  // 2) depthwise conv + SiLU
  dwconv_silu_k<<<(BB * DIN * LL) / 256, 256, 0, stream>>>(xz, cw, cb, xc);
  // 3) prior -> direction gates
  p2w_k<<<(BB * LL) / 256, 256, 0, stream>>>(prior, alpha, w1, b1, bnw, bnb, bnm,
                                             bnv, w2, b2, Wgb);
  // 4) x_proj (pixel-indexed, all 4 direction weight sets)
  xproj_k<<<dim3(LL / 64, BB), 256, 0, stream>>>(xc, xpw, proj);
  // 5) zero merge accumulator (ws is poisoned / stale between calls)
  zero_k<<<(BB * DIN * LL) / 256, 256, 0, stream>>>(ym, BB * DIN * LL);
  // 6) selective scan + gate + cross-merge (atomic)
  scan_k<<<dim3(DIN, KK, BB), 256, 0, stream>>>(xc, proj, Wgb, dtw, dtb, A_logs,
                                                Ds, ym);
  // 7) LayerNorm(channel) * silu(z)  (writes into u == xc buffer)
  ln_silu_k<<<dim3(LL / 64, BB), 256, 0, stream>>>(ym, xz, onw, onb, u);
  // 8) out_proj GEMM: [B,192,L] -> [B,96,L]
  gemm_pix_k<DIN><<<dim3(LL / 1024, COUT / 8, BB), 256, 0, stream>>>(u, opw, out, COUT);
}

// Round 2
// 404.022 us; speedup vs baseline: 2.0898x; 2.0898x over previous
//
#include <hip/hip_runtime.h>
#include <math.h>

#define BB   8
#define CIN  96
#define DIN  192
#define HH   64
#define WW   64
#define LL   4096
#define KK   4
#define RR   6
#define COUT 96
#define SS   64   // scan segments
#define LC   64   // segment length = LL/SS

__device__ __forceinline__ float sigf(float x) { return 1.0f / (1.0f + __expf(-x)); }
__device__ __forceinline__ float softplusf_(float x) {
  return fmaxf(x, 0.0f) + log1pf(__expf(-fabsf(x)));
}
__device__ __forceinline__ int trp(int p) { return ((p & 63) << 6) | (p >> 6); }
__device__ __forceinline__ int pix_of(int k, int l) {
  if (k == 0) return l;
  if (k == 1) return trp(l);
  if (k == 2) return LL - 1 - l;
  return trp(LL - 1 - l);
}

// ---------------------------------------------------------------------------
// Per-pixel GEMM: out[b,o,p] = sum_c in[b,c,p] * W[o,c]
// ---------------------------------------------------------------------------
template <int C>
__global__ __launch_bounds__(256) void gemm_pix_k(const float* __restrict__ in,
                                                  const float* __restrict__ W,
                                                  float* __restrict__ out, int O) {
  __shared__ float sW[C * 8];
  const int tid = threadIdx.x;
  const int b  = blockIdx.z;
  const int o0 = blockIdx.y * 8;
  const int p0 = blockIdx.x * 1024;
  for (int idx = tid; idx < C * 8; idx += 256) {
    int c = idx >> 3, j = idx & 7;
    sW[idx] = W[(o0 + j) * C + c];
  }
  __syncthreads();
  float acc[4][8];
#pragma unroll
  for (int jp = 0; jp < 4; ++jp)
#pragma unroll
    for (int j = 0; j < 8; ++j) acc[jp][j] = 0.0f;
  const float* inb = in + (size_t)b * C * LL + p0 + tid;
#pragma unroll 2
  for (int c = 0; c < C; ++c) {
    float xv[4];
#pragma unroll
    for (int jp = 0; jp < 4; ++jp) xv[jp] = inb[(size_t)c * LL + jp * 256];
    const float4 w0 = *(const float4*)&sW[c * 8];
    const float4 w1 = *(const float4*)&sW[c * 8 + 4];
#pragma unroll
    for (int jp = 0; jp < 4; ++jp) {
      acc[jp][0] = fmaf(xv[jp], w0.x, acc[jp][0]);
      acc[jp][1] = fmaf(xv[jp], w0.y, acc[jp][1]);
      acc[jp][2] = fmaf(xv[jp], w0.z, acc[jp][2]);
      acc[jp][3] = fmaf(xv[jp], w0.w, acc[jp][3]);
      acc[jp][4] = fmaf(xv[jp], w1.x, acc[jp][4]);
      acc[jp][5] = fmaf(xv[jp], w1.y, acc[jp][5]);
      acc[jp][6] = fmaf(xv[jp], w1.z, acc[jp][6]);
      acc[jp][7] = fmaf(xv[jp], w1.w, acc[jp][7]);
    }
  }
  float* ob = out + (size_t)b * O * LL + p0 + tid;
#pragma unroll
  for (int j = 0; j < 8; ++j)
#pragma unroll
    for (int jp = 0; jp < 4; ++jp) ob[(size_t)(o0 + j) * LL + jp * 256] = acc[jp][j];
}

// ---------------------------------------------------------------------------
// Depthwise 3x3 conv + bias + SiLU. xz[:,0:DIN] -> xc [B,DIN,L]
// ---------------------------------------------------------------------------
__global__ __launch_bounds__(256) void dwconv_silu_k(const float* __restrict__ xz,
                                                     const float* __restrict__ cw,
                                                     const float* __restrict__ cb,
                                                     float* __restrict__ xc) {
  int idx = blockIdx.x * 256 + threadIdx.x;
  int p  = idx & (LL - 1);
  int bd = idx >> 12;
  int d  = bd % DIN;
  int b  = bd / DIN;
  int h = p >> 6, w = p & 63;
  const float* xp = xz + ((size_t)b * 384 + d) * LL;
  float s = cb[d];
#pragma unroll
  for (int dh = -1; dh <= 1; ++dh) {
    int hh = h + dh;
    if (hh < 0 || hh >= HH) continue;
#pragma unroll
    for (int dw = -1; dw <= 1; ++dw) {
      int ww = w + dw;
      if (ww < 0 || ww >= WW) continue;
      s = fmaf(xp[hh * WW + ww], cw[d * 9 + (dh + 1) * 3 + (dw + 1)], s);
    }
  }
  xc[((size_t)b * DIN + d) * LL + p] = s * sigf(s);
}

// ---------------------------------------------------------------------------
// PriorToWeights MLP -> Wg[B,4,L]
// ---------------------------------------------------------------------------
__global__ __launch_bounds__(256) void p2w_k(const float* __restrict__ prior,
                                             const float* __restrict__ alpha,
                                             const float* __restrict__ w1,
                                             const float* __restrict__ b1,
                                             const float* __restrict__ bnw,
                                             const float* __restrict__ bnb,
                                             const float* __restrict__ bnm,
                                             const float* __restrict__ bnv,
                                             const float* __restrict__ w2,
                                             const float* __restrict__ b2,
                                             float* __restrict__ Wg) {
  int idx = blockIdx.x * 256 + threadIdx.x;
  int p = idx & (LL - 1);
  int b = idx >> 12;
  float pr[4];
#pragma unroll
  for (int c = 0; c < 4; ++c) pr[c] = prior[((size_t)b * 4 + c) * LL + p];
  float s = sigf(alpha[0]);
  float g2[4];
#pragma unroll
  for (int j = 0; j < 4; ++j) g2[j] = b2[j];
  for (int o = 0; o < 32; ++o) {
    float g = b1[o];
#pragma unroll
    for (int c = 0; c < 4; ++c) g = fmaf(pr[c], w1[o * 4 + c], g);
    g = (g - bnm[o]) * rsqrtf(bnv[o] + 1e-5f) * bnw[o] + bnb[o];
    g = fmaxf(g, 0.0f);
#pragma unroll
    for (int j = 0; j < 4; ++j) g2[j] = fmaf(g, w2[j * 32 + o], g2[j]);
  }
#pragma unroll
  for (int j = 0; j < 4; ++j)
    Wg[((size_t)b * 4 + j) * LL + p] = 1.0f + s * (sigf(g2[j]) - 1.0f);
}

// ---------------------------------------------------------------------------
// x_proj + transpose: xc[B,D,L] -> projS[B,K,8,L] (SCAN order) + xcT[B,L,D]
// block: 64 pixels (one image row), 256 thr = 64 px x 4 k
// ---------------------------------------------------------------------------
__global__ __launch_bounds__(256) void xprojT_k(const float* __restrict__ xc,
                                                const float* __restrict__ xpw,
                                                float* __restrict__ projS,
                                                float* __restrict__ xcT) {
  __shared__ float sW[KK * DIN * 8];   // 24 KB
  __shared__ float sX[64 * 193];       // 49.4 KB, pad 193 -> conflict-free
  const int tid = threadIdx.x;
  const int b  = blockIdx.y;
  const int p0 = blockIdx.x * 64;
  for (int idx = tid; idx < KK * DIN * 8; idx += 256) {
    int k = idx / (DIN * 8);
    int rem = idx % (DIN * 8);
    int dd = rem >> 3, c = rem & 7;
    sW[idx] = xpw[(k * 8 + c) * DIN + dd];
  }
  // stage xc tile: coalesced global (px fast), conflict-free LDS (px+d banks)
  for (int idx = tid; idx < DIN * 64; idx += 256) {
    int dd = idx >> 6, px = idx & 63;
    sX[px * 193 + dd] = xc[((size_t)b * DIN + dd) * LL + p0 + px];
  }
  __syncthreads();
  // write transposed copy xcT (coalesced: d fast)
  for (int idx = tid; idx < 64 * DIN; idx += 256) {
    int pp = idx / DIN, dd = idx % DIN;
    xcT[((size_t)b * LL + p0 + pp) * DIN + dd] = sX[pp * 193 + dd];
  }
  // compute proj for this pixel, all 4 direction weight sets
  const int px = tid & 63, k = tid >> 6;
  const int p = p0 + px;
  float acc[8];
#pragma unroll
  for (int c = 0; c < 8; ++c) acc[c] = 0.0f;
  for (int dd = 0; dd < DIN; ++dd) {
    float xv = sX[px * 193 + dd];
    const float4 w0 = *(const float4*)&sW[(k * DIN + dd) * 8];
    const float4 w1 = *(const float4*)&sW[(k * DIN + dd) * 8 + 4];
    acc[0] = fmaf(xv, w0.x, acc[0]);
    acc[1] = fmaf(xv, w0.y, acc[1]);
    acc[2] = fmaf(xv, w0.z, acc[2]);
    acc[3] = fmaf(xv, w0.w, acc[3]);
    acc[4] = fmaf(xv, w1.x, acc[4]);
    acc[5] = fmaf(xv, w1.y, acc[5]);
    acc[6] = fmaf(xv, w1.z, acc[6]);
    acc[7] = fmaf(xv, w1.w, acc[7]);
  }
  // scan-order position of pixel p in direction k
  int l;
  if (k == 0) l = p;
  else if (k == 1) l = trp(p);
  else if (k == 2) l = LL - 1 - p;
  else l = LL - 1 - trp(p);
  float* pb = projS + ((size_t)(b * KK + k)) * 8 * LL + l;
#pragma unroll
  for (int c = 0; c < 8; ++c) pb[(size_t)c * LL] = acc[c];
}

// ---------------------------------------------------------------------------
// Scan pass 1: per-segment carries (P,H). thread = d, block = (seg,k,b)
// ---------------------------------------------------------------------------
__global__ __launch_bounds__(192) void scan_part_k(const float* __restrict__ xcT,
                                                   const float* __restrict__ projS,
                                                   const float* __restrict__ dtw,
                                                   const float* __restrict__ dtb,
                                                   const float* __restrict__ A_logs,
                                                   float* __restrict__ carrP,
                                                   float* __restrict__ carrH) {
  const int s = blockIdx.x, k = blockIdx.y, b = blockIdx.z;
  const int d = threadIdx.x;
  __shared__ float sPr[8 * LC];
  const float* prb = projS + ((size_t)(b * KK + k)) * 8 * LL + s * LC;
  for (int idx = d; idx < 8 * LC; idx += 192) {
    int c = idx >> 6, j = idx & 63;
    sPr[idx] = prb[(size_t)c * LL + j];
  }
  __syncthreads();
  const int kd = k * DIN + d;
  float wr[6];
#pragma unroll
  for (int r = 0; r < 6; ++r) wr[r] = dtw[kd * 6 + r];
  const float bias = dtb[kd];
  const float Aa = -__expf(A_logs[kd]);
  float P = 1.0f, h = 0.0f;
#pragma unroll 4
  for (int j = 0; j < LC; ++j) {
    int p = pix_of(k, s * LC + j);
    float xv = xcT[((size_t)b * LL + p) * DIN + d];
    float dtr = bias;
#pragma unroll
    for (int r = 0; r < 6; ++r) dtr = fmaf(sPr[r * LC + j], wr[r], dtr);
    float dt = softplusf_(dtr);
    float a = __expf(dt * Aa);
    h = fmaf(a, h, dt * sPr[6 * LC + j] * xv);
    P *= a;
  }
  size_t o = ((size_t)((b * KK + k) * SS + s)) * DIN + d;
  carrP[o] = P;
  carrH[o] = h;
}

// ---------------------------------------------------------------------------
// Scan pass 2: serial combine of SS carries -> per-segment initial state h0
// ---------------------------------------------------------------------------
__global__ __launch_bounds__(192) void scan_fix_k(const float* __restrict__ carrP,
                                                  const float* __restrict__ carrH,
                                                  float* __restrict__ h0) {
  const int k = blockIdx.x, b = blockIdx.y, d = threadIdx.x;
  size_t base = ((size_t)(b * KK + k)) * SS * DIN + d;
  float h = 0.0f;
  for (int s = 0; s < SS; ++s) {
    h0[base + (size_t)s * DIN] = h;
    h = fmaf(carrP[base + (size_t)s * DIN], h, carrH[base + (size_t)s * DIN]);
  }
}

// ---------------------------------------------------------------------------
// Scan pass 3: apply + gate + merge opposite directions (no atomics).
// pair kp=0: k=0 fwd + k=2 rev -> ymT[b,p,d]   (row-major pixel rows)
// pair kp=1: k=1 fwd + k=3 rev -> ymT2[b,t,d]  (t = transposed-pixel index)
// ---------------------------------------------------------------------------
__global__ __launch_bounds__(192) void scan_apply_k(const float* __restrict__ xcT,
                                                    const float* __restrict__ projS,
                                                    const float* __restrict__ Wg,
                                                    const float* __restrict__ h0,
                                                    const float* __restrict__ dtw,
                                                    const float* __restrict__ dtb,
                                                    const float* __restrict__ A_logs,
                                                    const float* __restrict__ Ds,
                                                    float* __restrict__ ymT,
                                                    float* __restrict__ ymT2) {
  const int s = blockIdx.x, kp = blockIdx.y, b = blockIdx.z;
  const int d = threadIdx.x;
  const int kA = kp, kB = kp + 2;
  const int s2 = SS - 1 - s;
  __shared__ float sPrA[8 * LC], sPrB[8 * LC], swA[LC], swB[LC];
  __shared__ float sAcc[LC * DIN];  // 48 KB, column d private to thread d
  const float* prA = projS + ((size_t)(b * KK + kA)) * 8 * LL + s * LC;
  const float* prB = projS + ((size_t)(b * KK + kB)) * 8 * LL + s2 * LC;
  for (int idx = d; idx < 8 * LC; idx += 192) {
    int c = idx >> 6, j = idx & 63;
    sPrA[idx] = prA[(size_t)c * LL + j];
    sPrB[idx] = prB[(size_t)c * LL + j];
  }
  for (int idx = d; idx < LC; idx += 192) {
    swA[idx] = Wg[((size_t)(b * KK + kA)) * LL + s * LC + idx];
    swB[idx] = Wg[((size_t)(b * KK + kB)) * LL + s2 * LC + idx];
  }
  __syncthreads();
  // --- direction A: forward over its segment s ---
  {
    const int kd = kA * DIN + d;
    float wr[6];
#pragma unroll
    for (int r = 0; r < 6; ++r) wr[r] = dtw[kd * 6 + r];
    const float bias = dtb[kd];
    const float Aa = -__expf(A_logs[kd]);
    const float Dv = Ds[kd];
    float h = h0[((size_t)((b * KK + kA) * SS + s)) * DIN + d];
#pragma unroll 4
    for (int j = 0; j < LC; ++j) {
      int p = pix_of(kA, s * LC + j);
      float xv = xcT[((size_t)b * LL + p) * DIN + d];
      float dtr = bias;
#pragma unroll
      for (int r = 0; r < 6; ++r) dtr = fmaf(sPrA[r * LC + j], wr[r], dtr);
      float dt = softplusf_(dtr);
      float a = __expf(dt * Aa);
      h = fmaf(a, h, dt * sPrA[6 * LC + j] * xv);
      sAcc[j * DIN + d] = fmaf(h, sPrA[7 * LC + j], Dv * xv) * swA[j];
    }
  }
  // --- direction B: its segment s2 visits the same pixels/rows in reverse ---
  {
    const int kd = kB * DIN + d;
    float wr[6];
#pragma unroll
    for (int r = 0; r < 6; ++r) wr[r] = dtw[kd * 6 + r];
    const float bias = dtb[kd];
    const float Aa = -__expf(A_logs[kd]);
    const float Dv = Ds[kd];
    float h = h0[((size_t)((b * KK + kB) * SS + s2)) * DIN + d];
#pragma unroll 4
    for (int j = 0; j < LC; ++j) {
      int p = pix_of(kB, s2 * LC + j);
      float xv = xcT[((size_t)b * LL + p) * DIN + d];
      float dtr = bias;
#pragma unroll
      for (int r = 0; r < 6; ++r) dtr = fmaf(sPrB[r * LC + j], wr[r], dtr);
      float dt = softplusf_(dtr);
      float a = __expf(dt * Aa);
      h = fmaf(a, h, dt * sPrB[6 * LC + j] * xv);
      float y = fmaf(h, sPrB[7 * LC + j], Dv * xv) * swB[j];
      sAcc[(LC - 1 - j) * DIN + d] += y;  // same thread-column: no race
    }
  }
  // flush (column d is thread-private: no sync needed)
  float* dst = (kp == 0 ? ymT : ymT2) + ((size_t)b * LL + s * LC) * DIN + d;
  for (int j = 0; j < LC; ++j) dst[(size_t)j * DIN] = sAcc[j * DIN + d];
}

// ---------------------------------------------------------------------------
// LayerNorm(channel) * silu(z): reads ymT[p,:] + ymT2[tr(p),:], writes u[B,D,L]
// ---------------------------------------------------------------------------
__global__ __launch_bounds__(256) void ln_silu_k(const float* __restrict__ ymT,
                                                 const float* __restrict__ ymT2,
                                                 const float* __restrict__ xz,
                                                 const float* __restrict__ gamma,
                                                 const float* __restrict__ beta,
                                                 float* __restrict__ u) {
  const int b = blockIdx.y;
  const int h = blockIdx.x;       // tile = one image row
  const int p0 = h * 64;
  __shared__ float sY[64 * 193];
  __shared__ float sS[4][64], sQ[4][64];
  const int tid = threadIdx.x;
  for (int idx = tid; idx < 64 * DIN; idx += 256) {
    int pp = idx / DIN, dd = idx % DIN;
    float v = ymT[((size_t)b * LL + p0 + pp) * DIN + dd] +
              ymT2[((size_t)b * LL + pp * 64 + h) * DIN + dd];
    sY[pp * 193 + dd] = v;
  }
  __syncthreads();
  const int px = tid & 63, g = tid >> 6;
  float sum = 0.0f, ss = 0.0f;
  for (int dd = g * 48; dd < g * 48 + 48; ++dd) {
    float v = sY[px * 193 + dd];
    sum += v;
    ss = fmaf(v, v, ss);
  }
  sS[g][px] = sum;
  sQ[g][px] = ss;
  __syncthreads();
  sum = sS[0][px] + sS[1][px] + sS[2][px] + sS[3][px];
  ss  = sQ[0][px] + sQ[1][px] + sQ[2][px] + sQ[3][px];
  const float mu = sum * (1.0f / DIN);
  float var = ss * (1.0f / DIN) - mu * mu;
  const float rstd = rsqrtf(fmaxf(var, 0.0f) + 1e-5f);
  const float* zb = xz + ((size_t)b * 384 + DIN) * LL + p0 + px;
  float* ub = u + (size_t)b * DIN * LL + p0 + px;
  for (int dd = g * 48; dd < g * 48 + 48; ++dd) {
    float v = sY[px * 193 + dd];
    float z = zb[(size_t)dd * LL];
    float tn = fmaf((v - mu) * rstd, gamma[dd], beta[dd]);
    ub[(size_t)dd * LL] = tn * (z * sigf(z));
  }
}

// ---------------------------------------------------------------------------
extern "C" void kernel_launch(void* const* d_in, const int* in_sizes, int n_in,
                              void* d_out, int out_size, void* d_ws, size_t ws_size,
                              hipStream_t stream) {
  const float* x      = (const float*)d_in[0];
  const float* prior  = (const float*)d_in[1];
  const float* alpha  = (const float*)d_in[2];
  const float* ipw    = (const float*)d_in[3];
  const float* cw     = (const float*)d_in[4];
  const float* cb     = (const float*)d_in[5];
  const float* xpw    = (const float*)d_in[6];
  const float* dtw    = (const float*)d_in[7];
  const float* dtb    = (const float*)d_in[8];
  const float* A_logs = (const float*)d_in[9];
  const float* Ds     = (const float*)d_in[10];
  const float* onw    = (const float*)d_in[11];
  const float* onb    = (const float*)d_in[12];
  const float* opw    = (const float*)d_in[13];
  const float* w1     = (const float*)d_in[14];
  const float* b1     = (const float*)d_in[15];
  const float* bnw    = (const float*)d_in[16];
  const float* bnb    = (const float*)d_in[17];
  const float* bnm    = (const float*)d_in[18];
  const float* bnv    = (const float*)d_in[19];
  const float* w2     = (const float*)d_in[20];
  const float* b2     = (const float*)d_in[21];
  float* out = (float*)d_out;

  char* ws = (char*)d_ws;
  float* xz    = (float*)(ws);                       // [B,384,L]   50.3 MB
  float* xc    = (float*)(ws + 50331648);            // [B,192,L]   25.2 MB (-> ymT)
  float* xcT   = (float*)(ws + 75497472);            // [B,L,192]   25.2 MB (-> u)
  float* projS = (float*)(ws + 100663296);           // [B,4,8,L]    4.2 MB scan-order
  float* Wgb   = (float*)(ws + 104857600);           // [B,4,L]      0.5 MB
  float* ymT2  = (float*)(ws + 105381888);           // [B,L,192]   25.2 MB
  float* carrP = (float*)(ws + 130547712);           // [B,4,S,192]  1.6 MB
  float* carrH = (float*)(ws + 132120576);           // [B,4,S,192]  1.6 MB
  float* h0b   = (float*)(ws + 133693440);           // [B,4,S,192]  1.6 MB
  float* ymT = xc;   // xc dead after xprojT_k
  float* u   = xcT;  // xcT dead after scan_apply_k

  // 1) in_proj GEMM
  gemm_pix_k<CIN><<<dim3(LL / 1024, 384 / 8, BB), 256, 0, stream>>>(x, ipw, xz, 384);
  // 2) depthwise conv + SiLU
  dwconv_silu_k<<<(BB * DIN * LL) / 256, 256, 0, stream>>>(xz, cw, cb, xc);
  // 3) prior -> direction gates
  p2w_k<<<(BB * LL) / 256, 256, 0, stream>>>(prior, alpha, w1, b1, bnw, bnb, bnm,
                                             bnv, w2, b2, Wgb);
  // 4) x_proj (scan-order) + pixel-major transpose
  xprojT_k<<<dim3(LL / 64, BB), 256, 0, stream>>>(xc, xpw, projS, xcT);
  // 5) scan: segment carries
  scan_part_k<<<dim3(SS, KK, BB), 192, 0, stream>>>(xcT, projS, dtw, dtb, A_logs,
                                                    carrP, carrH);
  // 6) scan: serial carry combine
  scan_fix_k<<<dim3(KK, BB), 192, 0, stream>>>(carrP, carrH, h0b);
  // 7) scan: apply + gate + paired-direction merge (no atomics)
  scan_apply_k<<<dim3(SS, 2, BB), 192, 0, stream>>>(xcT, projS, Wgb, h0b, dtw, dtb,
                                                    A_logs, Ds, ymT, ymT2);
  // 8) LayerNorm(channel) * silu(z)
  ln_silu_k<<<dim3(HH, BB), 256, 0, stream>>>(ymT, ymT2, xz, onw, onb, u);
  // 9) out_proj GEMM
  gemm_pix_k<DIN><<<dim3(LL / 1024, COUT / 8, BB), 256, 0, stream>>>(u, opw, out, COUT);
}

// Round 8
// 260.436 us; speedup vs baseline: 3.2419x; 1.5513x over previous
//
#include <hip/hip_runtime.h>

#define BB   8
#define CIN  96
#define DIN  192
#define HH   64
#define WW   64
#define LL   4096
#define KK   4
#define COUT 96
#define SS   128  // scan segments
#define LC   32   // segment length = LL/SS

#define LOG2E 1.4426950408889634f
#define LN2   0.6931471805599453f

__device__ __forceinline__ float exp2fast(float x) { return __builtin_amdgcn_exp2f(x); }
__device__ __forceinline__ float log2fast(float x) { return __builtin_amdgcn_logf(x); }
__device__ __forceinline__ float sigf(float x) { return 1.0f / (1.0f + __expf(-x)); }
__device__ __forceinline__ int trp(int p) { return ((p & 63) << 6) | (p >> 6); }
__device__ __forceinline__ int pix_of(int k, int l) {
  if (k == 0) return l;
  if (k == 1) return trp(l);
  if (k == 2) return LL - 1 - l;
  return trp(LL - 1 - l);
}

// ---------------------------------------------------------------------------
// Per-pixel GEMM: out[b,o,p] = sum_c in[b,c,p] * W[o,c]
// ---------------------------------------------------------------------------
template <int C>
__global__ __launch_bounds__(256) void gemm_pix_k(const float* __restrict__ in,
                                                  const float* __restrict__ W,
                                                  float* __restrict__ out, int O) {
  __shared__ float sW[C * 8];
  const int tid = threadIdx.x;
  const int b  = blockIdx.z;
  const int o0 = blockIdx.y * 8;
  const int p0 = blockIdx.x * 1024;
  for (int idx = tid; idx < C * 8; idx += 256) {
    int c = idx >> 3, j = idx & 7;
    sW[idx] = W[(o0 + j) * C + c];
  }
  __syncthreads();
  float acc[4][8];
#pragma unroll
  for (int jp = 0; jp < 4; ++jp)
#pragma unroll
    for (int j = 0; j < 8; ++j) acc[jp][j] = 0.0f;
  const float* inb = in + (size_t)b * C * LL + p0 + tid;
#pragma unroll 2
  for (int c = 0; c < C; ++c) {
    float xv[4];
#pragma unroll
    for (int jp = 0; jp < 4; ++jp) xv[jp] = inb[(size_t)c * LL + jp * 256];
    const float4 w0 = *(const float4*)&sW[c * 8];
    const float4 w1 = *(const float4*)&sW[c * 8 + 4];
#pragma unroll
    for (int jp = 0; jp < 4; ++jp) {
      acc[jp][0] = fmaf(xv[jp], w0.x, acc[jp][0]);
      acc[jp][1] = fmaf(xv[jp], w0.y, acc[jp][1]);
      acc[jp][2] = fmaf(xv[jp], w0.z, acc[jp][2]);
      acc[jp][3] = fmaf(xv[jp], w0.w, acc[jp][3]);
      acc[jp][4] = fmaf(xv[jp], w1.x, acc[jp][4]);
      acc[jp][5] = fmaf(xv[jp], w1.y, acc[jp][5]);
      acc[jp][6] = fmaf(xv[jp], w1.z, acc[jp][6]);
      acc[jp][7] = fmaf(xv[jp], w1.w, acc[jp][7]);
    }
  }
  float* ob = out + (size_t)b * O * LL + p0 + tid;
#pragma unroll
  for (int j = 0; j < 8; ++j)
#pragma unroll
    for (int jp = 0; jp < 4; ++jp) ob[(size_t)(o0 + j) * LL + jp * 256] = acc[jp][j];
}

// ---------------------------------------------------------------------------
// PriorToWeights MLP -> Wg[B,4,L]
// ---------------------------------------------------------------------------
__global__ __launch_bounds__(256) void p2w_k(const float* __restrict__ prior,
                                             const float* __restrict__ alpha,
                                             const float* __restrict__ w1,
                                             const float* __restrict__ b1,
                                             const float* __restrict__ bnw,
                                             const float* __restrict__ bnb,
                                             const float* __restrict__ bnm,
                                             const float* __restrict__ bnv,
                                             const float* __restrict__ w2,
                                             const float* __restrict__ b2,
                                             float* __restrict__ Wg) {
  int idx = blockIdx.x * 256 + threadIdx.x;
  int p = idx & (LL - 1);
  int b = idx >> 12;
  float pr[4];
#pragma unroll
  for (int c = 0; c < 4; ++c) pr[c] = prior[((size_t)b * 4 + c) * LL + p];
  float s = sigf(alpha[0]);
  float g2[4];
#pragma unroll
  for (int j = 0; j < 4; ++j) g2[j] = b2[j];
  for (int o = 0; o < 32; ++o) {
    float g = b1[o];
#pragma unroll
    for (int c = 0; c < 4; ++c) g = fmaf(pr[c], w1[o * 4 + c], g);
    g = (g - bnm[o]) * rsqrtf(bnv[o] + 1e-5f) * bnw[o] + bnb[o];
    g = fmaxf(g, 0.0f);
#pragma unroll
    for (int j = 0; j < 4; ++j) g2[j] = fmaf(g, w2[j * 32 + o], g2[j]);
  }
#pragma unroll
  for (int j = 0; j < 4; ++j)
    Wg[((size_t)b * 4 + j) * LL + p] = 1.0f + s * (sigf(g2[j]) - 1.0f);
}

// ---------------------------------------------------------------------------
// FUSED: depthwise 3x3 conv + SiLU -> x_proj (scan-order) + transpose xcT.
// ---------------------------------------------------------------------------
__global__ __launch_bounds__(256) void convproj_k(const float* __restrict__ xz,
                                                  const float* __restrict__ cw,
                                                  const float* __restrict__ cb,
                                                  const float* __restrict__ xpw,
                                                  float* __restrict__ xcT,
                                                  float* __restrict__ projS) {
  __shared__ float sW[KK * DIN * 8];   // 24 KB
  __shared__ float sX[64 * 193];       // 49.4 KB
  const int tid = threadIdx.x;
  const int b = blockIdx.y;
  const int h = blockIdx.x;
  for (int idx = tid; idx < KK * DIN * 8; idx += 256) {
    int k = idx / (DIN * 8);
    int rem = idx % (DIN * 8);
    int dd = rem >> 3, c = rem & 7;
    sW[idx] = xpw[(k * 8 + c) * DIN + dd];
  }
  // depthwise conv + bias + SiLU directly into LDS tile
  for (int idx = tid; idx < DIN * 64; idx += 256) {
    int dd = idx >> 6, px = idx & 63;
    const float* xp = xz + ((size_t)b * 384 + dd) * LL + h * 64 + px;
    const float* wp = cw + dd * 9;
    float s = cb[dd];
#pragma unroll
    for (int dh = -1; dh <= 1; ++dh) {
      int hh = h + dh;
      if (hh < 0 || hh >= HH) continue;
      const float* row = xp + dh * 64;
      float w0 = wp[(dh + 1) * 3], w1 = wp[(dh + 1) * 3 + 1], w2 = wp[(dh + 1) * 3 + 2];
      if (px > 0) s = fmaf(row[-1], w0, s);
      s = fmaf(row[0], w1, s);
      if (px < 63) s = fmaf(row[1], w2, s);
    }
    sX[px * 193 + dd] = s * sigf(s);
  }
  __syncthreads();
  // transposed copy xcT[b][p][d]
  for (int idx = tid; idx < 64 * DIN; idx += 256) {
    int pp = idx / DIN, dd = idx % DIN;
    xcT[((size_t)b * LL + h * 64 + pp) * DIN + dd] = sX[pp * 193 + dd];
  }
  // x_proj for this pixel, all 4 direction weight sets; write scan-order [b][k][l][8]
  const int px = tid & 63, k = tid >> 6;
  const int p = h * 64 + px;
  float acc[8];
#pragma unroll
  for (int c = 0; c < 8; ++c) acc[c] = 0.0f;
  for (int dd = 0; dd < DIN; ++dd) {
    float xv = sX[px * 193 + dd];
    const float4 w0 = *(const float4*)&sW[(k * DIN + dd) * 8];
    const float4 w1 = *(const float4*)&sW[(k * DIN + dd) * 8 + 4];
    acc[0] = fmaf(xv, w0.x, acc[0]);
    acc[1] = fmaf(xv, w0.y, acc[1]);
    acc[2] = fmaf(xv, w0.z, acc[2]);
    acc[3] = fmaf(xv, w0.w, acc[3]);
    acc[4] = fmaf(xv, w1.x, acc[4]);
    acc[5] = fmaf(xv, w1.y, acc[5]);
    acc[6] = fmaf(xv, w1.z, acc[6]);
    acc[7] = fmaf(xv, w1.w, acc[7]);
  }
  int l;
  if (k == 0) l = p;
  else if (k == 1) l = trp(p);
  else if (k == 2) l = LL - 1 - p;
  else l = LL - 1 - trp(p);
  float* pb = projS + (((size_t)b * KK + k) * LL + l) * 8;
  *(float4*)pb = make_float4(acc[0], acc[1], acc[2], acc[3]);
  *(float4*)(pb + 4) = make_float4(acc[4], acc[5], acc[6], acc[7]);
}

// ---------------------------------------------------------------------------
// Scan pass 1: per-segment carries (P,H). thread = d, block = (seg,k,b).
// ---------------------------------------------------------------------------
__global__ __launch_bounds__(192) void scan_part_k(const float* __restrict__ xcT,
                                                   const float* __restrict__ projS,
                                                   const float* __restrict__ dtw,
                                                   const float* __restrict__ dtb,
                                                   const float* __restrict__ A_logs,
                                                   float* __restrict__ carrP,
                                                   float* __restrict__ carrH) {
  const int s = blockIdx.x, k = blockIdx.y, b = blockIdx.z;
  const int d = threadIdx.x;
  const int kd = k * DIN + d;
  float wr[6];
#pragma unroll
  for (int r = 0; r < 6; ++r) wr[r] = dtw[kd * 6 + r];
  const float bias = dtb[kd];
  const float Aa = -__expf(A_logs[kd]);
  const int l0 = s * LC;
  const int p0 = pix_of(k, l0);
  const int dp = pix_of(k, l0 + 1) - p0;
  const float* xp = xcT + ((size_t)b * LL + p0) * DIN + d;
  const long xstep = (long)dp * DIN;
  const float* pr = projS + (((size_t)b * KK + k) * LL + l0) * 8;
  float P = 1.0f, h = 0.0f;
#pragma unroll 4
  for (int j = 0; j < LC; ++j) {
    float4 q0 = *(const float4*)pr;
    float4 q1 = *(const float4*)(pr + 4);
    pr += 8;
    float xv = *xp;
    xp += xstep;
    float dtr = bias;
    dtr = fmaf(q0.x, wr[0], dtr);
    dtr = fmaf(q0.y, wr[1], dtr);
    dtr = fmaf(q0.z, wr[2], dtr);
    dtr = fmaf(q0.w, wr[3], dtr);
    dtr = fmaf(q1.x, wr[4], dtr);
    dtr = fmaf(q1.y, wr[5], dtr);
    float e = exp2fast(fminf(dtr, 80.0f) * LOG2E);
    float u = log2fast(1.0f + e);      // softplus in base-2
    float a = exp2fast(u * Aa);        // exp(dt*Aa) = 2^(u*Aa)
    float dt = u * LN2;
    h = fmaf(a, h, dt * q1.z * xv);
    P *= a;
  }
  size_t o = ((size_t)((b * KK + k) * SS + s)) * DIN + d;
  carrP[o] = P;
  carrH[o] = h;
}

// ---------------------------------------------------------------------------
// Scan pass 2: serial combine of SS carries -> per-segment initial state h0
// ---------------------------------------------------------------------------
__global__ __launch_bounds__(192) void scan_fix_k(const float* __restrict__ carrP,
                                                  const float* __restrict__ carrH,
                                                  float* __restrict__ h0) {
  const int k = blockIdx.x, b = blockIdx.y, d = threadIdx.x;
  size_t base = ((size_t)(b * KK + k)) * SS * DIN + d;
  float h = 0.0f;
#pragma unroll 4
  for (int s = 0; s < SS; ++s) {
    h0[base + (size_t)s * DIN] = h;
    h = fmaf(carrP[base + (size_t)s * DIN], h, carrH[base + (size_t)s * DIN]);
  }
}

// ---------------------------------------------------------------------------
// Scan pass 3: apply + gate + paired-direction merge via 24 KB LDS.
// pair kp=0: k=0 + k=2 -> ymT (overlaid on xz x_ssm half, b-stride 384*LL)
// pair kp=1: k=1 + k=3 -> ymT2[b,t,d]
// ---------------------------------------------------------------------------
__global__ __launch_bounds__(192) void scan_apply_k(const float* __restrict__ xcT,
                                                    const float* __restrict__ projS,
                                                    const float* __restrict__ Wg,
                                                    const float* __restrict__ h0,
                                                    const float* __restrict__ dtw,
                                                    const float* __restrict__ dtb,
                                                    const float* __restrict__ A_logs,
                                                    const float* __restrict__ Ds,
                                                    float* __restrict__ ymT,
                                                    float* __restrict__ ymT2) {
  const int s = blockIdx.x, kp = blockIdx.y, b = blockIdx.z;
  const int d = threadIdx.x;
  __shared__ float sAcc[LC * DIN];  // 24 KB, column d thread-private
  // ---- direction A = kp, segment s ----
  {
    const int k = kp, kd = k * DIN + d;
    float wr[6];
#pragma unroll
    for (int r = 0; r < 6; ++r) wr[r] = dtw[kd * 6 + r];
    const float bias = dtb[kd];
    const float Aa = -__expf(A_logs[kd]);
    const float Dv = Ds[kd];
    const int l0 = s * LC;
    const int p0 = pix_of(k, l0);
    const int dp = pix_of(k, l0 + 1) - p0;
    const float* xp = xcT + ((size_t)b * LL + p0) * DIN + d;
    const long xstep = (long)dp * DIN;
    const float* pr = projS + (((size_t)b * KK + k) * LL + l0) * 8;
    const float* wg = Wg + ((size_t)b * KK + k) * LL + l0;
    float h = h0[((size_t)((b * KK + k) * SS + s)) * DIN + d];
#pragma unroll 4
    for (int j = 0; j < LC; ++j) {
      float4 q0 = *(const float4*)pr;
      float4 q1 = *(const float4*)(pr + 4);
      pr += 8;
      float xv = *xp;
      xp += xstep;
      float dtr = bias;
      dtr = fmaf(q0.x, wr[0], dtr);
      dtr = fmaf(q0.y, wr[1], dtr);
      dtr = fmaf(q0.z, wr[2], dtr);
      dtr = fmaf(q0.w, wr[3], dtr);
      dtr = fmaf(q1.x, wr[4], dtr);
      dtr = fmaf(q1.y, wr[5], dtr);
      float e = exp2fast(fminf(dtr, 80.0f) * LOG2E);
      float u = log2fast(1.0f + e);
      float a = exp2fast(u * Aa);
      float dt = u * LN2;
      h = fmaf(a, h, dt * q1.z * xv);
      sAcc[j * DIN + d] = fmaf(h, q1.w, Dv * xv) * wg[j];
    }
  }
  // ---- direction B = kp+2, segment SS-1-s (same pixels, reversed) ----
  {
    const int k = kp + 2, kd = k * DIN + d;
    const int s2 = SS - 1 - s;
    float wr[6];
#pragma unroll
    for (int r = 0; r < 6; ++r) wr[r] = dtw[kd * 6 + r];
    const float bias = dtb[kd];
    const float Aa = -__expf(A_logs[kd]);
    const float Dv = Ds[kd];
    const int l0 = s2 * LC;
    const int p0 = pix_of(k, l0);
    const int dp = pix_of(k, l0 + 1) - p0;
    const float* xp = xcT + ((size_t)b * LL + p0) * DIN + d;
    const long xstep = (long)dp * DIN;
    const float* pr = projS + (((size_t)b * KK + k) * LL + l0) * 8;
    const float* wg = Wg + ((size_t)b * KK + k) * LL + l0;
    float h = h0[((size_t)((b * KK + k) * SS + s2)) * DIN + d];
#pragma unroll 4
    for (int j = 0; j < LC; ++j) {
      float4 q0 = *(const float4*)pr;
      float4 q1 = *(const float4*)(pr + 4);
      pr += 8;
      float xv = *xp;
      xp += xstep;
      float dtr = bias;
      dtr = fmaf(q0.x, wr[0], dtr);
      dtr = fmaf(q0.y, wr[1], dtr);
      dtr = fmaf(q0.z, wr[2], dtr);
      dtr = fmaf(q0.w, wr[3], dtr);
      dtr = fmaf(q1.x, wr[4], dtr);
      dtr = fmaf(q1.y, wr[5], dtr);
      float e = exp2fast(fminf(dtr, 80.0f) * LOG2E);
      float u = log2fast(1.0f + e);
      float a = exp2fast(u * Aa);
      float dt = u * LN2;
      h = fmaf(a, h, dt * q1.z * xv);
      float y = fmaf(h, q1.w, Dv * xv) * wg[j];
      sAcc[(LC - 1 - j) * DIN + d] += y;  // same thread-column: no race
    }
  }
  // flush (no sync needed: column d thread-private)
  float* dst;
  if (kp == 0)
    dst = ymT + (size_t)b * (384 * (size_t)LL) + (size_t)(s * LC) * DIN + d;  // xz overlay
  else
    dst = ymT2 + ((size_t)b * LL + s * LC) * DIN + d;
#pragma unroll 4
  for (int j = 0; j < LC; ++j) dst[(size_t)j * DIN] = sAcc[j * DIN + d];
}

// ---------------------------------------------------------------------------
// LayerNorm(channel) * silu(z): reads ymT(overlay)[p,:] + ymT2[tr(p),:], writes u
// ---------------------------------------------------------------------------
__global__ __launch_bounds__(256) void ln_silu_k(const float* __restrict__ ymT,
                                                 const float* __restrict__ ymT2,
                                                 const float* __restrict__ xz,
                                                 const float* __restrict__ gamma,
                                                 const float* __restrict__ beta,
                                                 float* __restrict__ u) {
  const int b = blockIdx.y;
  const int h = blockIdx.x;
  const int p0 = h * 64;
  __shared__ float sY[64 * 193];
  __shared__ float sS[4][64], sQ[4][64];
  const int tid = threadIdx.x;
  const float* ymb = ymT + (size_t)b * (384 * (size_t)LL);  // xz overlay, b-stride 384*L
  for (int idx = tid; idx < 64 * DIN; idx += 256) {
    int pp = idx / DIN, dd = idx % DIN;
    float v = ymb[(size_t)(p0 + pp) * DIN + dd] +
              ymT2[((size_t)b * LL + pp * 64 + h) * DIN + dd];
    sY[pp * 193 + dd] = v;
  }
  __syncthreads();
  const int px = tid & 63, g = tid >> 6;
  float sum = 0.0f, ss = 0.0f;
  for (int dd = g * 48; dd < g * 48 + 48; ++dd) {
    float v = sY[px * 193 + dd];
    sum += v;
    ss = fmaf(v, v, ss);
  }
  sS[g][px] = sum;
  sQ[g][px] = ss;
  __syncthreads();
  sum = sS[0][px] + sS[1][px] + sS[2][px] + sS[3][px];
  ss  = sQ[0][px] + sQ[1][px] + sQ[2][px] + sQ[3][px];
  const float mu = sum * (1.0f / DIN);
  float var = ss * (1.0f / DIN) - mu * mu;
  const float rstd = rsqrtf(fmaxf(var, 0.0f) + 1e-5f);
  const float* zb = xz + ((size_t)b * 384 + DIN) * LL + p0 + px;
  float* ub = u + (size_t)b * DIN * LL + p0 + px;
  for (int dd = g * 48; dd < g * 48 + 48; ++dd) {
    float v = sY[px * 193 + dd];
    float z = zb[(size_t)dd * LL];
    float tn = fmaf((v - mu) * rstd, gamma[dd], beta[dd]);
    ub[(size_t)dd * LL] = tn * (z * sigf(z));
  }
}

// ---------------------------------------------------------------------------
extern "C" void kernel_launch(void* const* d_in, const int* in_sizes, int n_in,
                              void* d_out, int out_size, void* d_ws, size_t ws_size,
                              hipStream_t stream) {
  const float* x      = (const float*)d_in[0];
  const float* prior  = (const float*)d_in[1];
  const float* alpha  = (const float*)d_in[2];
  const float* ipw    = (const float*)d_in[3];
  const float* cw     = (const float*)d_in[4];
  const float* cb     = (const float*)d_in[5];
  const float* xpw    = (const float*)d_in[6];
  const float* dtw    = (const float*)d_in[7];
  const float* dtb    = (const float*)d_in[8];
  const float* A_logs = (const float*)d_in[9];
  const float* Ds     = (const float*)d_in[10];
  const float* onw    = (const float*)d_in[11];
  const float* onb    = (const float*)d_in[12];
  const float* opw    = (const float*)d_in[13];
  const float* w1     = (const float*)d_in[14];
  const float* b1     = (const float*)d_in[15];
  const float* bnw    = (const float*)d_in[16];
  const float* bnb    = (const float*)d_in[17];
  const float* bnm    = (const float*)d_in[18];
  const float* bnv    = (const float*)d_in[19];
  const float* w2     = (const float*)d_in[20];
  const float* b2     = (const float*)d_in[21];
  float* out = (float*)d_out;

  char* ws = (char*)d_ws;
  // Carry buffers with SS=128 are 3,145,728 B EACH (was the bug: spaced 1.5 MB).
  // Footprint ends at 114,819,072 B (< 135,266,304 B proven in R2).
  float* xz    = (float*)(ws);              // [B,384,L]     50.3 MB
  float* xcT   = (float*)(ws + 50331648);   // [B,L,192]     25.2 MB (-> u after apply)
  float* ymT2  = (float*)(ws + 75497472);   // [B,L,192]     25.2 MB
  float* projS = (float*)(ws + 100663296);  // [B,K,L,8]      4.2 MB (scan order)
  float* Wgb   = (float*)(ws + 104857600);  // [B,4,L]        0.5 MB
  float* carrP = (float*)(ws + 105381888);  // [B,K,SS,192]   3.0 MB
  float* carrH = (float*)(ws + 108527616);  // [B,K,SS,192]   3.0 MB
  float* h0b   = (float*)(ws + 111673344);  // [B,K,SS,192]   3.0 MB (ends 114819072)
  float* ymT   = xz;   // overlay: x_ssm half of xz (dead after convproj), b-stride 384*L
  float* u     = xcT;  // xcT dead after scan_apply_k

  // 1) in_proj GEMM: [B,96,L] -> [B,384,L]
  gemm_pix_k<CIN><<<dim3(LL / 1024, 384 / 8, BB), 256, 0, stream>>>(x, ipw, xz, 384);
  // 2) prior -> direction gates
  p2w_k<<<(BB * LL) / 256, 256, 0, stream>>>(prior, alpha, w1, b1, bnw, bnb, bnm,
                                             bnv, w2, b2, Wgb);
  // 3) fused dwconv+SiLU + x_proj(scan-order) + transpose
  convproj_k<<<dim3(HH, BB), 256, 0, stream>>>(xz, cw, cb, xpw, xcT, projS);
  // 4) scan: segment carries
  scan_part_k<<<dim3(SS, KK, BB), 192, 0, stream>>>(xcT, projS, dtw, dtb, A_logs,
                                                    carrP, carrH);
  // 5) scan: serial carry combine
  scan_fix_k<<<dim3(KK, BB), 192, 0, stream>>>(carrP, carrH, h0b);
  // 6) scan: apply + gate + paired merge (ymT overlaid on xz x_ssm half)
  scan_apply_k<<<dim3(SS, 2, BB), 192, 0, stream>>>(xcT, projS, Wgb, h0b, dtw, dtb,
                                                    A_logs, Ds, ymT, ymT2);
  // 7) LayerNorm(channel) * silu(z)
  ln_silu_k<<<dim3(HH, BB), 256, 0, stream>>>(ymT, ymT2, xz, onw, onb, u);
  // 8) out_proj GEMM
  gemm_pix_k<DIN><<<dim3(LL / 1024, COUT / 8, BB), 256, 0, stream>>>(u, opw, out, COUT);
}

// Round 9
// 257.670 us; speedup vs baseline: 3.2767x; 1.0107x over previous
//
#include <hip/hip_runtime.h>

#define BB   8
#define CIN  96
#define DIN  192
#define HH   64
#define WW   64
#define LL   4096
#define KK   4
#define COUT 96
#define SS   128  // scan segments
#define LC   32   // segment length = LL/SS

#define LOG2E 1.4426950408889634f
#define LN2   0.6931471805599453f

__device__ __forceinline__ float exp2fast(float x) { return __builtin_amdgcn_exp2f(x); }
__device__ __forceinline__ float log2fast(float x) { return __builtin_amdgcn_logf(x); }
__device__ __forceinline__ float sigf(float x) { return 1.0f / (1.0f + __expf(-x)); }
__device__ __forceinline__ int trp(int p) { return ((p & 63) << 6) | (p >> 6); }
__device__ __forceinline__ int pix_of(int k, int l) {
  if (k == 0) return l;
  if (k == 1) return trp(l);
  if (k == 2) return LL - 1 - l;
  return trp(LL - 1 - l);
}

// ---------------------------------------------------------------------------
// Per-pixel GEMM: out[b,o,p] = sum_c in[b,c,p] * W[o,c]
// ---------------------------------------------------------------------------
template <int C>
__global__ __launch_bounds__(256) void gemm_pix_k(const float* __restrict__ in,
                                                  const float* __restrict__ W,
                                                  float* __restrict__ out, int O) {
  __shared__ float sW[C * 8];
  const int tid = threadIdx.x;
  const int b  = blockIdx.z;
  const int o0 = blockIdx.y * 8;
  const int p0 = blockIdx.x * 1024;
  for (int idx = tid; idx < C * 8; idx += 256) {
    int c = idx >> 3, j = idx & 7;
    sW[idx] = W[(o0 + j) * C + c];
  }
  __syncthreads();
  float acc[4][8];
#pragma unroll
  for (int jp = 0; jp < 4; ++jp)
#pragma unroll
    for (int j = 0; j < 8; ++j) acc[jp][j] = 0.0f;
  const float* inb = in + (size_t)b * C * LL + p0 + tid;
#pragma unroll 2
  for (int c = 0; c < C; ++c) {
    float xv[4];
#pragma unroll
    for (int jp = 0; jp < 4; ++jp) xv[jp] = inb[(size_t)c * LL + jp * 256];
    const float4 w0 = *(const float4*)&sW[c * 8];
    const float4 w1 = *(const float4*)&sW[c * 8 + 4];
#pragma unroll
    for (int jp = 0; jp < 4; ++jp) {
      acc[jp][0] = fmaf(xv[jp], w0.x, acc[jp][0]);
      acc[jp][1] = fmaf(xv[jp], w0.y, acc[jp][1]);
      acc[jp][2] = fmaf(xv[jp], w0.z, acc[jp][2]);
      acc[jp][3] = fmaf(xv[jp], w0.w, acc[jp][3]);
      acc[jp][4] = fmaf(xv[jp], w1.x, acc[jp][4]);
      acc[jp][5] = fmaf(xv[jp], w1.y, acc[jp][5]);
      acc[jp][6] = fmaf(xv[jp], w1.z, acc[jp][6]);
      acc[jp][7] = fmaf(xv[jp], w1.w, acc[jp][7]);
    }
  }
  float* ob = out + (size_t)b * O * LL + p0 + tid;
#pragma unroll
  for (int j = 0; j < 8; ++j)
#pragma unroll
    for (int jp = 0; jp < 4; ++jp) ob[(size_t)(o0 + j) * LL + jp * 256] = acc[jp][j];
}

// ---------------------------------------------------------------------------
// PriorToWeights MLP -> Wg[B,4,L].  Block 0 also transposes x_proj_weight
// into xpwT[k][dd][8] for convproj_k (consumer launches later; no race).
// ---------------------------------------------------------------------------
__global__ __launch_bounds__(256) void p2w_k(const float* __restrict__ prior,
                                             const float* __restrict__ alpha,
                                             const float* __restrict__ w1,
                                             const float* __restrict__ b1,
                                             const float* __restrict__ bnw,
                                             const float* __restrict__ bnb,
                                             const float* __restrict__ bnm,
                                             const float* __restrict__ bnv,
                                             const float* __restrict__ w2,
                                             const float* __restrict__ b2,
                                             const float* __restrict__ xpw,
                                             float* __restrict__ xpwT,
                                             float* __restrict__ Wg) {
  if (blockIdx.x == 0) {
    for (int idx = threadIdx.x; idx < KK * DIN * 8; idx += 256) {
      int kk = idx / (DIN * 8);
      int rem = idx % (DIN * 8);
      int dd = rem >> 3, c = rem & 7;
      xpwT[idx] = xpw[(kk * 8 + c) * DIN + dd];
    }
  }
  int idx = blockIdx.x * 256 + threadIdx.x;
  int p = idx & (LL - 1);
  int b = idx >> 12;
  float pr[4];
#pragma unroll
  for (int c = 0; c < 4; ++c) pr[c] = prior[((size_t)b * 4 + c) * LL + p];
  float s = sigf(alpha[0]);
  float g2[4];
#pragma unroll
  for (int j = 0; j < 4; ++j) g2[j] = b2[j];
  for (int o = 0; o < 32; ++o) {
    float g = b1[o];
#pragma unroll
    for (int c = 0; c < 4; ++c) g = fmaf(pr[c], w1[o * 4 + c], g);
    g = (g - bnm[o]) * rsqrtf(bnv[o] + 1e-5f) * bnw[o] + bnb[o];
    g = fmaxf(g, 0.0f);
#pragma unroll
    for (int j = 0; j < 4; ++j) g2[j] = fmaf(g, w2[j * 32 + o], g2[j]);
  }
#pragma unroll
  for (int j = 0; j < 4; ++j)
    Wg[((size_t)b * 4 + j) * LL + p] = 1.0f + s * (sigf(g2[j]) - 1.0f);
}

// ---------------------------------------------------------------------------
// FUSED conv+proj v2: two 96-channel halves through a 25 KB LDS tile; weights
// via wave-uniform global loads from xpwT (no sW LDS). 6 blocks/CU.
// ---------------------------------------------------------------------------
__global__ __launch_bounds__(256) void convproj_k(const float* __restrict__ xz,
                                                  const float* __restrict__ cw,
                                                  const float* __restrict__ cb,
                                                  const float* __restrict__ xpwT,
                                                  float* __restrict__ xcT,
                                                  float* __restrict__ projS) {
  __shared__ float sX[96 * 65];  // 24.96 KB
  const int tid = threadIdx.x;
  const int b = blockIdx.y;
  const int h = blockIdx.x;
  const int px = tid & 63;
  const int ku = __builtin_amdgcn_readfirstlane(tid >> 6);  // wave-uniform k
  const float* wpk = xpwT + (size_t)ku * (DIN * 8);
  float acc[8];
#pragma unroll
  for (int c = 0; c < 8; ++c) acc[c] = 0.0f;

#pragma unroll
  for (int half = 0; half < 2; ++half) {
    // conv + bias + SiLU for channels [half*96, half*96+96) into sX[ddl][px]
    for (int idx = tid; idx < 96 * 64; idx += 256) {
      int ddl = idx >> 6, pxx = idx & 63;
      int dd = half * 96 + ddl;
      const float* xp = xz + ((size_t)b * 384 + dd) * LL + h * 64 + pxx;
      const float* wp = cw + dd * 9;
      float s = cb[dd];
#pragma unroll
      for (int dh = -1; dh <= 1; ++dh) {
        int hh = h + dh;
        if (hh < 0 || hh >= HH) continue;
        const float* row = xp + dh * 64;
        float w0 = wp[(dh + 1) * 3], w1 = wp[(dh + 1) * 3 + 1], w2 = wp[(dh + 1) * 3 + 2];
        if (pxx > 0) s = fmaf(row[-1], w0, s);
        s = fmaf(row[0], w1, s);
        if (pxx < 63) s = fmaf(row[1], w2, s);
      }
      sX[ddl * 65 + pxx] = s * sigf(s);
    }
    __syncthreads();
    // transposed write xcT[b][p][half*96 + ddl] (coalesced in ddl)
    for (int idx = tid; idx < 64 * 96; idx += 256) {
      int pp = idx / 96, ddl = idx % 96;
      xcT[((size_t)b * LL + h * 64 + pp) * DIN + half * 96 + ddl] = sX[ddl * 65 + pp];
    }
    // x_proj partial accumulation over this half's channels
    const float* wp = wpk + half * 96 * 8;
    for (int ddl = 0; ddl < 96; ++ddl) {
      float xv = sX[ddl * 65 + px];
      const float4 w0 = *(const float4*)(wp + ddl * 8);
      const float4 w1 = *(const float4*)(wp + ddl * 8 + 4);
      acc[0] = fmaf(xv, w0.x, acc[0]);
      acc[1] = fmaf(xv, w0.y, acc[1]);
      acc[2] = fmaf(xv, w0.z, acc[2]);
      acc[3] = fmaf(xv, w0.w, acc[3]);
      acc[4] = fmaf(xv, w1.x, acc[4]);
      acc[5] = fmaf(xv, w1.y, acc[5]);
      acc[6] = fmaf(xv, w1.z, acc[6]);
      acc[7] = fmaf(xv, w1.w, acc[7]);
    }
    __syncthreads();  // protect sX before next half overwrites
  }
  // write projS in scan order [b][k][l][8]
  const int p = h * 64 + px;
  int l;
  if (ku == 0) l = p;
  else if (ku == 1) l = trp(p);
  else if (ku == 2) l = LL - 1 - p;
  else l = LL - 1 - trp(p);
  float* pb = projS + (((size_t)b * KK + ku) * LL + l) * 8;
  *(float4*)pb = make_float4(acc[0], acc[1], acc[2], acc[3]);
  *(float4*)(pb + 4) = make_float4(acc[4], acc[5], acc[6], acc[7]);
}

// ---------------------------------------------------------------------------
// Scan pass 1: per-segment carries (P,H). thread = d, block = (seg,k,b).
// ---------------------------------------------------------------------------
__global__ __launch_bounds__(192) void scan_part_k(const float* __restrict__ xcT,
                                                   const float* __restrict__ projS,
                                                   const float* __restrict__ dtw,
                                                   const float* __restrict__ dtb,
                                                   const float* __restrict__ A_logs,
                                                   float* __restrict__ carrP,
                                                   float* __restrict__ carrH) {
  const int s = blockIdx.x, k = blockIdx.y, b = blockIdx.z;
  const int d = threadIdx.x;
  const int kd = k * DIN + d;
  float wr[6];
#pragma unroll
  for (int r = 0; r < 6; ++r) wr[r] = dtw[kd * 6 + r];
  const float bias = dtb[kd];
  const float Aa = -__expf(A_logs[kd]);
  const int l0 = s * LC;
  const int p0 = pix_of(k, l0);
  const int dp = pix_of(k, l0 + 1) - p0;
  const float* xp = xcT + ((size_t)b * LL + p0) * DIN + d;
  const long xstep = (long)dp * DIN;
  const float* pr = projS + (((size_t)b * KK + k) * LL + l0) * 8;
  float P = 1.0f, h = 0.0f;
#pragma unroll 4
  for (int j = 0; j < LC; ++j) {
    float4 q0 = *(const float4*)pr;
    float4 q1 = *(const float4*)(pr + 4);
    pr += 8;
    float xv = *xp;
    xp += xstep;
    float dtr = bias;
    dtr = fmaf(q0.x, wr[0], dtr);
    dtr = fmaf(q0.y, wr[1], dtr);
    dtr = fmaf(q0.z, wr[2], dtr);
    dtr = fmaf(q0.w, wr[3], dtr);
    dtr = fmaf(q1.x, wr[4], dtr);
    dtr = fmaf(q1.y, wr[5], dtr);
    float e = exp2fast(fminf(dtr, 80.0f) * LOG2E);
    float u = log2fast(1.0f + e);      // softplus in base-2
    float a = exp2fast(u * Aa);        // exp(dt*Aa) = 2^(u*Aa)
    float dt = u * LN2;
    h = fmaf(a, h, dt * q1.z * xv);
    P *= a;
  }
  size_t o = ((size_t)((b * KK + k) * SS + s)) * DIN + d;
  carrP[o] = P;
  carrH[o] = h;
}

// ---------------------------------------------------------------------------
// Scan pass 2: serial combine of SS carries -> per-segment initial state h0
// ---------------------------------------------------------------------------
__global__ __launch_bounds__(192) void scan_fix_k(const float* __restrict__ carrP,
                                                  const float* __restrict__ carrH,
                                                  float* __restrict__ h0) {
  const int k = blockIdx.x, b = blockIdx.y, d = threadIdx.x;
  size_t base = ((size_t)(b * KK + k)) * SS * DIN + d;
  float h = 0.0f;
#pragma unroll 4
  for (int s = 0; s < SS; ++s) {
    h0[base + (size_t)s * DIN] = h;
    h = fmaf(carrP[base + (size_t)s * DIN], h, carrH[base + (size_t)s * DIN]);
  }
}

// ---------------------------------------------------------------------------
// Scan pass 3: apply + gate + paired-direction merge via 24 KB LDS.
// pair kp=0: k=0 + k=2 -> ymT (overlaid on xz x_ssm half, b-stride 384*LL)
// pair kp=1: k=1 + k=3 -> ymT2[b,t,d]
// ---------------------------------------------------------------------------
__global__ __launch_bounds__(192) void scan_apply_k(const float* __restrict__ xcT,
                                                    const float* __restrict__ projS,
                                                    const float* __restrict__ Wg,
                                                    const float* __restrict__ h0,
                                                    const float* __restrict__ dtw,
                                                    const float* __restrict__ dtb,
                                                    const float* __restrict__ A_logs,
                                                    const float* __restrict__ Ds,
                                                    float* __restrict__ ymT,
                                                    float* __restrict__ ymT2) {
  const int s = blockIdx.x, kp = blockIdx.y, b = blockIdx.z;
  const int d = threadIdx.x;
  __shared__ float sAcc[LC * DIN];  // 24 KB, column d thread-private
  // ---- direction A = kp, segment s ----
  {
    const int k = kp, kd = k * DIN + d;
    float wr[6];
#pragma unroll
    for (int r = 0; r < 6; ++r) wr[r] = dtw[kd * 6 + r];
    const float bias = dtb[kd];
    const float Aa = -__expf(A_logs[kd]);
    const float Dv = Ds[kd];
    const int l0 = s * LC;
    const int p0 = pix_of(k, l0);
    const int dp = pix_of(k, l0 + 1) - p0;
    const float* xp = xcT + ((size_t)b * LL + p0) * DIN + d;
    const long xstep = (long)dp * DIN;
    const float* pr = projS + (((size_t)b * KK + k) * LL + l0) * 8;
    const float* wg = Wg + ((size_t)b * KK + k) * LL + l0;
    float h = h0[((size_t)((b * KK + k) * SS + s)) * DIN + d];
#pragma unroll 4
    for (int j = 0; j < LC; ++j) {
      float4 q0 = *(const float4*)pr;
      float4 q1 = *(const float4*)(pr + 4);
      pr += 8;
      float xv = *xp;
      xp += xstep;
      float dtr = bias;
      dtr = fmaf(q0.x, wr[0], dtr);
      dtr = fmaf(q0.y, wr[1], dtr);
      dtr = fmaf(q0.z, wr[2], dtr);
      dtr = fmaf(q0.w, wr[3], dtr);
      dtr = fmaf(q1.x, wr[4], dtr);
      dtr = fmaf(q1.y, wr[5], dtr);
      float e = exp2fast(fminf(dtr, 80.0f) * LOG2E);
      float u = log2fast(1.0f + e);
      float a = exp2fast(u * Aa);
      float dt = u * LN2;
      h = fmaf(a, h, dt * q1.z * xv);
      sAcc[j * DIN + d] = fmaf(h, q1.w, Dv * xv) * wg[j];
    }
  }
  // ---- direction B = kp+2, segment SS-1-s (same pixels, reversed) ----
  {
    const int k = kp + 2, kd = k * DIN + d;
    const int s2 = SS - 1 - s;
    float wr[6];
#pragma unroll
    for (int r = 0; r < 6; ++r) wr[r] = dtw[kd * 6 + r];
    const float bias = dtb[kd];
    const float Aa = -__expf(A_logs[kd]);
    const float Dv = Ds[kd];
    const int l0 = s2 * LC;
    const int p0 = pix_of(k, l0);
    const int dp = pix_of(k, l0 + 1) - p0;
    const float* xp = xcT + ((size_t)b * LL + p0) * DIN + d;
    const long xstep = (long)dp * DIN;
    const float* pr = projS + (((size_t)b * KK + k) * LL + l0) * 8;
    const float* wg = Wg + ((size_t)b * KK + k) * LL + l0;
    float h = h0[((size_t)((b * KK + k) * SS + s2)) * DIN + d];
#pragma unroll 4
    for (int j = 0; j < LC; ++j) {
      float4 q0 = *(const float4*)pr;
      float4 q1 = *(const float4*)(pr + 4);
      pr += 8;
      float xv = *xp;
      xp += xstep;
      float dtr = bias;
      dtr = fmaf(q0.x, wr[0], dtr);
      dtr = fmaf(q0.y, wr[1], dtr);
      dtr = fmaf(q0.z, wr[2], dtr);
      dtr = fmaf(q0.w, wr[3], dtr);
      dtr = fmaf(q1.x, wr[4], dtr);
      dtr = fmaf(q1.y, wr[5], dtr);
      float e = exp2fast(fminf(dtr, 80.0f) * LOG2E);
      float u = log2fast(1.0f + e);
      float a = exp2fast(u * Aa);
      float dt = u * LN2;
      h = fmaf(a, h, dt * q1.z * xv);
      float y = fmaf(h, q1.w, Dv * xv) * wg[j];
      sAcc[(LC - 1 - j) * DIN + d] += y;  // same thread-column: no race
    }
  }
  // flush (no sync needed: column d thread-private)
  float* dst;
  if (kp == 0)
    dst = ymT + (size_t)b * (384 * (size_t)LL) + (size_t)(s * LC) * DIN + d;  // xz overlay
  else
    dst = ymT2 + ((size_t)b * LL + s * LC) * DIN + d;
#pragma unroll 4
  for (int j = 0; j < LC; ++j) dst[(size_t)j * DIN] = sAcc[j * DIN + d];
}

// ---------------------------------------------------------------------------
// LayerNorm(channel) * silu(z): reads ymT(overlay)[p,:] + ymT2[tr(p),:], writes u
// ---------------------------------------------------------------------------
__global__ __launch_bounds__(256) void ln_silu_k(const float* __restrict__ ymT,
                                                 const float* __restrict__ ymT2,
                                                 const float* __restrict__ xz,
                                                 const float* __restrict__ gamma,
                                                 const float* __restrict__ beta,
                                                 float* __restrict__ u) {
  const int b = blockIdx.y;
  const int h = blockIdx.x;
  const int p0 = h * 64;
  __shared__ float sY[64 * 193];
  __shared__ float sS[4][64], sQ[4][64];
  const int tid = threadIdx.x;
  const float* ymb = ymT + (size_t)b * (384 * (size_t)LL);  // xz overlay, b-stride 384*L
  for (int idx = tid; idx < 64 * DIN; idx += 256) {
    int pp = idx / DIN, dd = idx % DIN;
    float v = ymb[(size_t)(p0 + pp) * DIN + dd] +
              ymT2[((size_t)b * LL + pp * 64 + h) * DIN + dd];
    sY[pp * 193 + dd] = v;
  }
  __syncthreads();
  const int px = tid & 63, g = tid >> 6;
  float sum = 0.0f, ss = 0.0f;
  for (int dd = g * 48; dd < g * 48 + 48; ++dd) {
    float v = sY[px * 193 + dd];
    sum += v;
    ss = fmaf(v, v, ss);
  }
  sS[g][px] = sum;
  sQ[g][px] = ss;
  __syncthreads();
  sum = sS[0][px] + sS[1][px] + sS[2][px] + sS[3][px];
  ss  = sQ[0][px] + sQ[1][px] + sQ[2][px] + sQ[3][px];
  const float mu = sum * (1.0f / DIN);
  float var = ss * (1.0f / DIN) - mu * mu;
  const float rstd = rsqrtf(fmaxf(var, 0.0f) + 1e-5f);
  const float* zb = xz + ((size_t)b * 384 + DIN) * LL + p0 + px;
  float* ub = u + (size_t)b * DIN * LL + p0 + px;
  for (int dd = g * 48; dd < g * 48 + 48; ++dd) {
    float v = sY[px * 193 + dd];
    float z = zb[(size_t)dd * LL];
    float tn = fmaf((v - mu) * rstd, gamma[dd], beta[dd]);
    ub[(size_t)dd * LL] = tn * (z * sigf(z));
  }
}

// ---------------------------------------------------------------------------
extern "C" void kernel_launch(void* const* d_in, const int* in_sizes, int n_in,
                              void* d_out, int out_size, void* d_ws, size_t ws_size,
                              hipStream_t stream) {
  const float* x      = (const float*)d_in[0];
  const float* prior  = (const float*)d_in[1];
  const float* alpha  = (const float*)d_in[2];
  const float* ipw    = (const float*)d_in[3];
  const float* cw     = (const float*)d_in[4];
  const float* cb     = (const float*)d_in[5];
  const float* xpw    = (const float*)d_in[6];
  const float* dtw    = (const float*)d_in[7];
  const float* dtb    = (const float*)d_in[8];
  const float* A_logs = (const float*)d_in[9];
  const float* Ds     = (const float*)d_in[10];
  const float* onw    = (const float*)d_in[11];
  const float* onb    = (const float*)d_in[12];
  const float* opw    = (const float*)d_in[13];
  const float* w1     = (const float*)d_in[14];
  const float* b1     = (const float*)d_in[15];
  const float* bnw    = (const float*)d_in[16];
  const float* bnb    = (const float*)d_in[17];
  const float* bnm    = (const float*)d_in[18];
  const float* bnv    = (const float*)d_in[19];
  const float* w2     = (const float*)d_in[20];
  const float* b2     = (const float*)d_in[21];
  float* out = (float*)d_out;

  char* ws = (char*)d_ws;
  // Footprint ends at 114,843,648 B (< 135,266,304 proven in R2).
  float* xz    = (float*)(ws);              // [B,384,L]     50.3 MB
  float* xcT   = (float*)(ws + 50331648);   // [B,L,192]     25.2 MB (-> u after apply)
  float* ymT2  = (float*)(ws + 75497472);   // [B,L,192]     25.2 MB
  float* projS = (float*)(ws + 100663296);  // [B,K,L,8]      4.2 MB (scan order)
  float* Wgb   = (float*)(ws + 104857600);  // [B,4,L]        0.5 MB
  float* carrP = (float*)(ws + 105381888);  // [B,K,SS,192]   3.0 MB
  float* carrH = (float*)(ws + 108527616);  // [B,K,SS,192]   3.0 MB
  float* h0b   = (float*)(ws + 111673344);  // [B,K,SS,192]   3.0 MB
  float* xpwT  = (float*)(ws + 114819072);  // [K,DIN,8]      24.6 KB (ends 114843648)
  float* ymT   = xz;   // overlay: x_ssm half of xz (dead after convproj), b-stride 384*L
  float* u     = xcT;  // xcT dead after scan_apply_k

  // 1) in_proj GEMM: [B,96,L] -> [B,384,L]
  gemm_pix_k<CIN><<<dim3(LL / 1024, 384 / 8, BB), 256, 0, stream>>>(x, ipw, xz, 384);
  // 2) prior -> direction gates  (+ weight transpose in block 0)
  p2w_k<<<(BB * LL) / 256, 256, 0, stream>>>(prior, alpha, w1, b1, bnw, bnb, bnm,
                                             bnv, w2, b2, xpw, xpwT, Wgb);
  // 3) fused dwconv+SiLU + x_proj(scan-order) + transpose  (2-half LDS, 25 KB)
  convproj_k<<<dim3(HH, BB), 256, 0, stream>>>(xz, cw, cb, xpwT, xcT, projS);
  // 4) scan: segment carries
  scan_part_k<<<dim3(SS, KK, BB), 192, 0, stream>>>(xcT, projS, dtw, dtb, A_logs,
                                                    carrP, carrH);
  // 5) scan: serial carry combine
  scan_fix_k<<<dim3(KK, BB), 192, 0, stream>>>(carrP, carrH, h0b);
  // 6) scan: apply + gate + paired merge (ymT overlaid on xz x_ssm half)
  scan_apply_k<<<dim3(SS, 2, BB), 192, 0, stream>>>(xcT, projS, Wgb, h0b, dtw, dtb,
                                                    A_logs, Ds, ymT, ymT2);
  // 7) LayerNorm(channel) * silu(z)
  ln_silu_k<<<dim3(HH, BB), 256, 0, stream>>>(ymT, ymT2, xz, onw, onb, u);
  // 8) out_proj GEMM
  gemm_pix_k<DIN><<<dim3(LL / 1024, COUT / 8, BB), 256, 0, stream>>>(u, opw, out, COUT);
}